// Round 1
// baseline (517.713 us; speedup 1.0000x reference)
//
#include <hip/hip_runtime.h>
#include <math.h>

// Problem constants (fixed shapes from setup_inputs):
constexpr int D  = 64;   // feature channels
constexpr int H  = 32;   // hidden channels
constexpr int KN = 16;   // neighbors per point

// ---------------------------------------------------------------------------
// Kernel 1: f_ws[b*N+n][h] = ReLU( (W2[h,:] . feature[b,:,n]) * g2[h]/sqrt(1+eps) + b2[h] )
// f_ws layout [B, N, H] (H contiguous) so kernel 2's neighbor gather reads
// 128 contiguous bytes per index.
// ---------------------------------------------------------------------------
__global__ __launch_bounds__(256) void rfa_feat_kernel(
    const float* __restrict__ feature,  // [B, D, N]
    const float* __restrict__ W2,       // [H, D]
    const float* __restrict__ g2,
    const float* __restrict__ b2,
    float* __restrict__ f_ws,           // [B, N, H]
    int N, int total)
{
    int t = blockIdx.x * blockDim.x + threadIdx.x;
    if (t >= total) return;
    int b = t / N;
    int n = t - b * N;

    const float* fp = feature + (size_t)b * D * N + n;
    float x[D];
    #pragma unroll
    for (int c = 0; c < D; ++c) x[c] = fp[(size_t)c * N];  // lane-coalesced

    const float inv = rsqrtf(1.0f + 1e-5f);
    float4* dst = (float4*)(f_ws + (size_t)t * H);

    #pragma unroll 1
    for (int h0 = 0; h0 < H; h0 += 4) {
        float o[4];
        #pragma unroll
        for (int hh = 0; hh < 4; ++hh) {
            int h = h0 + hh;
            float s = 0.0f;
            #pragma unroll
            for (int c = 0; c < D; ++c) s = fmaf(W2[h * D + c], x[c], s);
            s = s * (g2[h] * inv) + b2[h];
            o[hh] = fmaxf(s, 0.0f);
        }
        dst[h0 >> 2] = make_float4(o[0], o[1], o[2], o[3]);
    }
}

// ---------------------------------------------------------------------------
// Kernel 2: per point n —
//   for k: p10 = [dist, rel, self_xyz, nbr_xyz]; fx = ReLU(BN(W1 @ p10));
//          fj = f_ws[b, idx[k], :];
//          t  = ReLU(BN(W3 @ [fj ; fx]));  maxv = max(maxv, t)
//   out[b,:,n] = ReLU(BN(W4 @ [maxv ; f_ws[b,n,:]]))
// ---------------------------------------------------------------------------
__global__ __launch_bounds__(256) void rfa_main_kernel(
    const float* __restrict__ xyz,      // [B, N, 3]
    const int*   __restrict__ nidx,     // [B, N, KN]
    const float* __restrict__ W1,       // [H, 10]
    const float* __restrict__ g1, const float* __restrict__ b1,
    const float* __restrict__ W3,       // [H, 2H]
    const float* __restrict__ g3, const float* __restrict__ b3,
    const float* __restrict__ W4,       // [D, 2H]
    const float* __restrict__ g4, const float* __restrict__ b4,
    const float* __restrict__ f_ws,     // [B, N, H]
    float* __restrict__ out,            // [B, D, N]
    int N, int total)
{
    int t = blockIdx.x * blockDim.x + threadIdx.x;
    if (t >= total) return;
    int b = t / N;
    int n = t - b * N;

    const float inv = rsqrtf(1.0f + 1e-5f);

    const float px = xyz[(size_t)t * 3 + 0];
    const float py = xyz[(size_t)t * 3 + 1];
    const float pz = xyz[(size_t)t * 3 + 2];

    float maxv[H];
    #pragma unroll
    for (int h = 0; h < H; ++h) maxv[h] = 0.0f;  // ReLU outputs >= 0, so 0 == -inf here

    const int* ip = nidx + (size_t)t * KN;

    #pragma unroll 1
    for (int k = 0; k < KN; ++k) {
        const int j = ip[k];

        const float* np_ = xyz + (size_t)(b * N + j) * 3;
        const float nx = np_[0], ny = np_[1], nz = np_[2];
        const float rx = px - nx, ry = py - ny, rz = pz - nz;
        const float dist = sqrtf(rx * rx + ry * ry + rz * rz);

        // f_xyz = ReLU(BN(W1 @ [dist, rx,ry,rz, px,py,pz, nx,ny,nz]))
        float fx[H];
        #pragma unroll
        for (int h = 0; h < H; ++h) {
            const float* w = W1 + h * 10;
            float s = w[0] * dist;
            s = fmaf(w[1], rx, s); s = fmaf(w[2], ry, s); s = fmaf(w[3], rz, s);
            s = fmaf(w[4], px, s); s = fmaf(w[5], py, s); s = fmaf(w[6], pz, s);
            s = fmaf(w[7], nx, s); s = fmaf(w[8], ny, s); s = fmaf(w[9], nz, s);
            fx[h] = fmaxf(s * (g1[h] * inv) + b1[h], 0.0f);
        }

        // gather neighbor hidden feature (128 contiguous bytes)
        float fj[H];
        const float4* fjp = (const float4*)(f_ws + (size_t)(b * N + j) * H);
        #pragma unroll
        for (int i = 0; i < H / 4; ++i) {
            float4 v = fjp[i];
            fj[4 * i + 0] = v.x; fj[4 * i + 1] = v.y;
            fj[4 * i + 2] = v.z; fj[4 * i + 3] = v.w;
        }

        // W3 @ [fj ; fx], BN, ReLU, running max
        #pragma unroll 2
        for (int h = 0; h < H; ++h) {
            const float* w = W3 + h * 2 * H;
            float s = 0.0f;
            #pragma unroll
            for (int c = 0; c < H; ++c) s = fmaf(w[c], fj[c], s);
            #pragma unroll
            for (int c = 0; c < H; ++c) s = fmaf(w[H + c], fx[c], s);
            float r = fmaxf(s * (g3[h] * inv) + b3[h], 0.0f);
            maxv[h] = fmaxf(maxv[h], r);
        }
    }

    // self hidden feature
    float fs[H];
    const float4* fsp = (const float4*)(f_ws + (size_t)t * H);
    #pragma unroll
    for (int i = 0; i < H / 4; ++i) {
        float4 v = fsp[i];
        fs[4 * i + 0] = v.x; fs[4 * i + 1] = v.y;
        fs[4 * i + 2] = v.z; fs[4 * i + 3] = v.w;
    }

    // out = ReLU(BN(W4 @ [maxv ; fs]))
    #pragma unroll 2
    for (int o = 0; o < D; ++o) {
        const float* w = W4 + o * 2 * H;
        float s = 0.0f;
        #pragma unroll
        for (int c = 0; c < H; ++c) s = fmaf(w[c], maxv[c], s);
        #pragma unroll
        for (int c = 0; c < H; ++c) s = fmaf(w[H + c], fs[c], s);
        out[((size_t)b * D + o) * N + n] = fmaxf(s * (g4[o] * inv) + b4[o], 0.0f);
    }
}

// ---------------------------------------------------------------------------
extern "C" void kernel_launch(void* const* d_in, const int* in_sizes, int n_in,
                              void* d_out, int out_size, void* d_ws, size_t ws_size,
                              hipStream_t stream) {
    // dict order: feature, xyz, neigh_idx, W1, W2, W3, W4, g1,b1, g2,b2, g3,b3, g4,b4
    const float* feature = (const float*)d_in[0];
    const float* xyz     = (const float*)d_in[1];
    const int*   nidx    = (const int*)  d_in[2];
    const float* W1      = (const float*)d_in[3];
    const float* W2      = (const float*)d_in[4];
    const float* W3      = (const float*)d_in[5];
    const float* W4      = (const float*)d_in[6];
    const float* g1      = (const float*)d_in[7];
    const float* b1      = (const float*)d_in[8];
    const float* g2      = (const float*)d_in[9];
    const float* b2      = (const float*)d_in[10];
    const float* g3      = (const float*)d_in[11];
    const float* b3      = (const float*)d_in[12];
    const float* g4      = (const float*)d_in[13];
    const float* b4      = (const float*)d_in[14];
    float* out  = (float*)d_out;
    float* f_ws = (float*)d_ws;   // [B, N, H] floats = 20.97 MB

    const int B = 4;
    const int N = in_sizes[1] / (B * 3);   // xyz is [B, N, 3]
    const int total = B * N;
    const int threads = 256;
    const int blocks = (total + threads - 1) / threads;

    rfa_feat_kernel<<<blocks, threads, 0, stream>>>(feature, W2, g2, b2, f_ws, N, total);
    rfa_main_kernel<<<blocks, threads, 0, stream>>>(xyz, nidx, W1, g1, b1, W3, g3, b3,
                                                    W4, g4, b4, f_ws, out, N, total);
}

// Round 2
// 224.299 us; speedup vs baseline: 2.3081x; 2.3081x over previous
//
#include <hip/hip_runtime.h>
#include <math.h>

typedef __bf16 bf16_t;
typedef bf16_t bf16x8 __attribute__((ext_vector_type(8)));
typedef bf16_t bf16x4 __attribute__((ext_vector_type(4)));
typedef float  f32x4  __attribute__((ext_vector_type(4)));

#define MFMA16(a, b, c) __builtin_amdgcn_mfma_f32_16x16x32_bf16(a, b, c, 0, 0, 0)

// 1/sqrt(1 + 1e-5), the BN eval-mode scale denominator
constexpr float BN_INV = 0.999995000037499687f;
constexpr int PPW = 8;  // points per wave in k2

// all-reduce max over the 16 lanes of a DPP row (lane&15 varying, quad fixed)
__device__ __forceinline__ float row_max16(float v) {
    union { float f; int i; } u, r;
    u.f = v; r.i = __builtin_amdgcn_update_dpp(0, u.i, 0x121, 0xF, 0xF, true); v = fmaxf(v, r.f); // ror:1
    u.f = v; r.i = __builtin_amdgcn_update_dpp(0, u.i, 0x122, 0xF, 0xF, true); v = fmaxf(v, r.f); // ror:2
    u.f = v; r.i = __builtin_amdgcn_update_dpp(0, u.i, 0x124, 0xF, 0xF, true); v = fmaxf(v, r.f); // ror:4
    u.f = v; r.i = __builtin_amdgcn_update_dpp(0, u.i, 0x128, 0xF, 0xF, true); v = fmaxf(v, r.f); // ror:8
    return v;
}

// ---------------------------------------------------------------------------
// K1: f = ReLU(BN(W2 @ feature))  -> bf16 table fbf[t][32]   (t = b*N+n)
// One wave per 16 points. MFMA 16x16x32: A = W2 (g2-folded), B = feature cols.
// ---------------------------------------------------------------------------
__global__ __launch_bounds__(256) void rfa_k1(
    const float* __restrict__ feature, const float* __restrict__ W2,
    const float* __restrict__ g2, const float* __restrict__ b2,
    bf16_t* __restrict__ fbf, int N, int nwaves)
{
    int gtid = blockIdx.x * 256 + threadIdx.x;
    int w = gtid >> 6, lane = gtid & 63;
    if (w >= nwaves) return;
    int pt = lane & 15, quad = lane >> 4;
    int T0 = w * 16;
    int b  = T0 / N;
    int nn = T0 - b * N + pt;          // point index within batch
    size_t T = (size_t)T0 + pt;        // global point index

    // A-frags: lane m = lane&15 -> h = mt*16 + m ; k = ks*32 + quad*8 + j
    bf16x8 A[2][2];
    #pragma unroll
    for (int mt = 0; mt < 2; ++mt) {
        int h = mt * 16 + pt;
        float sc = g2[h] * BN_INV;
        #pragma unroll
        for (int ks = 0; ks < 2; ++ks) {
            const float* src = W2 + h * 64 + ks * 32 + quad * 8;
            bf16x8 v;
            #pragma unroll
            for (int j = 0; j < 8; ++j) v[j] = (bf16_t)(src[j] * sc);
            A[mt][ks] = v;
        }
    }
    // B-frags: col n = lane&15 = pt ; k = ks*32 + quad*8 + j -> channel c
    bf16x8 Bf[2];
    #pragma unroll
    for (int ks = 0; ks < 2; ++ks) {
        bf16x8 v;
        #pragma unroll
        for (int j = 0; j < 8; ++j) {
            int c = ks * 32 + quad * 8 + j;
            v[j] = (bf16_t)feature[((size_t)b * 64 + c) * N + nn];
        }
        Bf[ks] = v;
    }
    f32x4 acc[2] = {f32x4{0,0,0,0}, f32x4{0,0,0,0}};
    #pragma unroll
    for (int mt = 0; mt < 2; ++mt) {
        acc[mt] = MFMA16(A[mt][0], Bf[0], acc[mt]);
        acc[mt] = MFMA16(A[mt][1], Bf[1], acc[mt]);
    }
    // C/D: col = lane&15 = pt ; row = quad*4 + r (+16*mt)
    #pragma unroll
    for (int mt = 0; mt < 2; ++mt) {
        bf16x4 o;
        #pragma unroll
        for (int r = 0; r < 4; ++r) {
            int h = mt * 16 + quad * 4 + r;
            o[r] = (bf16_t)fmaxf(acc[mt][r] + b2[h], 0.f);
        }
        *(bf16x4*)(fbf + T * 32 + mt * 16 + quad * 4) = o;
    }
}

// ---------------------------------------------------------------------------
// K2: per point: fx = ReLU(BN(W1 @ p10)) via MFMA (K padded to 32, bias as
// extra input channel), fj gathered from fbf, W3 MFMA over the 16 neighbor
// columns, DPP max over columns, bias+ReLU, store bf16 maxv[t][32].
// One wave per point, PPW points per wave.
// ---------------------------------------------------------------------------
__global__ __launch_bounds__(256) void rfa_k2(
    const float* __restrict__ xyz, const int* __restrict__ nidx,
    const float* __restrict__ W1, const float* __restrict__ g1, const float* __restrict__ b1,
    const float* __restrict__ W3, const float* __restrict__ g3, const float* __restrict__ b3,
    const bf16_t* __restrict__ fbf, bf16_t* __restrict__ mv,
    int N, int total)
{
    __shared__ __align__(16) bf16_t sW3[32 * 72];   // g3-folded, row stride 72 (2-way bank free)
    __shared__ __align__(16) bf16_t sW1[32 * 56];   // g1-folded, padded K=32, col10 = b1
    __shared__ float sB[4 * 544];                    // per-wave bounce, row stride 17

    int tid = threadIdx.x;
    // stage W3 (32x64), fold g3*BN_INV
    {
        int h = tid >> 3, c0 = (tid & 7) * 8;
        float sc = g3[h] * BN_INV;
        bf16x8 v;
        #pragma unroll
        for (int j = 0; j < 8; ++j) v[j] = (bf16_t)(W3[h * 64 + c0 + j] * sc);
        *(bf16x8*)(sW3 + h * 72 + c0) = v;
    }
    // stage W1 padded [32][32]: c<10 = W1*g1*inv, c==10 = b1, else 0
    for (int i = tid; i < 1024; i += 256) {
        int h = i >> 5, c = i & 31;
        float v = 0.f;
        if (c < 10)       v = W1[h * 10 + c] * (g1[h] * BN_INV);
        else if (c == 10) v = b1[h];
        sW1[h * 56 + c] = (bf16_t)v;
    }
    __syncthreads();

    int lane = tid & 63, wv = tid >> 6;
    int n = lane & 15, quad = lane >> 4;

    // per-wave constants: A-frags + per-lane b3
    bf16x8 A3[2][2], A1[2];
    #pragma unroll
    for (int mt = 0; mt < 2; ++mt) {
        int h = mt * 16 + n;
        A3[mt][0] = *(const bf16x8*)(sW3 + h * 72 + quad * 8);
        A3[mt][1] = *(const bf16x8*)(sW3 + h * 72 + 32 + quad * 8);
        A1[mt]    = *(const bf16x8*)(sW1 + h * 56 + quad * 8);
    }
    float b3r[8];
    #pragma unroll
    for (int mt = 0; mt < 2; ++mt)
        #pragma unroll
        for (int r = 0; r < 4; ++r) b3r[mt * 4 + r] = b3[mt * 16 + quad * 4 + r];

    float* bounce = sB + wv * 544;
    int wg = blockIdx.x * 4 + wv;

    for (int p = 0; p < PPW; ++p) {
        int t = wg * PPW + p;
        if (t >= total) break;            // wave-uniform
        int b = t / N;
        int j = nidx[(size_t)t * 16 + n]; // this lane's neighbor (4-way dup across quads)
        float px = xyz[(size_t)t * 3 + 0];
        float py = xyz[(size_t)t * 3 + 1];
        float pz = xyz[(size_t)t * 3 + 2];
        const float* nb = xyz + ((size_t)(b * N + j)) * 3;
        float nx = nb[0], ny = nb[1], nz = nb[2];
        float rx = px - nx, ry = py - ny, rz = pz - nz;
        float dist = sqrtf(rx * rx + ry * ry + rz * rz);

        // B-frag for W1 mfma: p10 + bias channel. k = quad*8 + jj
        // quad0: [dist,rx,ry,rz,px,py,pz,nx]  quad1: [ny,nz,1,0,0,0,0,0]  quads2,3: 0
        float e0 = quad == 0 ? dist : (quad == 1 ? ny : 0.f);
        float e1 = quad == 0 ? rx   : (quad == 1 ? nz : 0.f);
        float e2 = quad == 0 ? ry   : (quad == 1 ? 1.f : 0.f);
        float e3 = quad == 0 ? rz : 0.f;
        float e4 = quad == 0 ? px : 0.f;
        float e5 = quad == 0 ? py : 0.f;
        float e6 = quad == 0 ? pz : 0.f;
        float e7 = quad == 0 ? nx : 0.f;
        bf16x8 Bp;
        Bp[0] = (bf16_t)e0; Bp[1] = (bf16_t)e1; Bp[2] = (bf16_t)e2; Bp[3] = (bf16_t)e3;
        Bp[4] = (bf16_t)e4; Bp[5] = (bf16_t)e5; Bp[6] = (bf16_t)e6; Bp[7] = (bf16_t)e7;

        f32x4 ax0 = {0,0,0,0}, ax1 = {0,0,0,0};
        ax0 = MFMA16(A1[0], Bp, ax0);
        ax1 = MFMA16(A1[1], Bp, ax1);

        // C-layout -> B-layout transform through the wave-private bounce
        #pragma unroll
        for (int r = 0; r < 4; ++r) {
            bounce[(quad * 4 + r) * 17 + n]        = fmaxf(ax0[r], 0.f);
            bounce[(16 + quad * 4 + r) * 17 + n]   = fmaxf(ax1[r], 0.f);
        }
        asm volatile("s_waitcnt lgkmcnt(0)" ::: "memory");
        bf16x8 Bx;
        #pragma unroll
        for (int jj = 0; jj < 8; ++jj)
            Bx[jj] = (bf16_t)bounce[(quad * 8 + jj) * 17 + n];

        // fj: 16B gather from the bf16 f table (k = quad*8+jj)
        bf16x8 Bj = *(const bf16x8*)(fbf + ((size_t)(b * N + j)) * 32 + quad * 8);

        f32x4 ac0 = {0,0,0,0}, ac1 = {0,0,0,0};
        ac0 = MFMA16(A3[0][0], Bj, ac0);
        ac0 = MFMA16(A3[0][1], Bx, ac0);
        ac1 = MFMA16(A3[1][0], Bj, ac1);
        ac1 = MFMA16(A3[1][1], Bx, ac1);

        // max over the 16 neighbor columns, then bias+ReLU (commutes with max)
        float o0[4], o1[4];
        #pragma unroll
        for (int r = 0; r < 4; ++r) {
            o0[r] = fmaxf(row_max16(ac0[r]) + b3r[r], 0.f);
            o1[r] = fmaxf(row_max16(ac1[r]) + b3r[4 + r], 0.f);
        }
        if (n == 0) {
            bf16x4 s0, s1;
            #pragma unroll
            for (int r = 0; r < 4; ++r) { s0[r] = (bf16_t)o0[r]; s1[r] = (bf16_t)o1[r]; }
            *(bf16x4*)(mv + (size_t)t * 32 + quad * 4)      = s0;
            *(bf16x4*)(mv + (size_t)t * 32 + 16 + quad * 4) = s1;
        }
        // drain bounce reads before next iteration's writes
        asm volatile("s_waitcnt lgkmcnt(0)" ::: "memory");
    }
}

// ---------------------------------------------------------------------------
// K3: out = ReLU(BN(W4 @ [maxv ; f]))  -> fp32 [B,64,N]
// One wave per 16 points, 8 MFMAs.
// ---------------------------------------------------------------------------
__global__ __launch_bounds__(256) void rfa_k3(
    const bf16_t* __restrict__ mv, const bf16_t* __restrict__ fbf,
    const float* __restrict__ W4, const float* __restrict__ g4, const float* __restrict__ b4,
    float* __restrict__ out, int N, int nwaves)
{
    int gtid = blockIdx.x * 256 + threadIdx.x;
    int w = gtid >> 6, lane = gtid & 63;
    if (w >= nwaves) return;
    int pt = lane & 15, quad = lane >> 4;
    int T0 = w * 16;
    int b  = T0 / N;
    int nn = T0 - b * N + pt;
    size_t T = (size_t)T0 + pt;

    bf16x8 A[4][2];
    #pragma unroll
    for (int mt = 0; mt < 4; ++mt) {
        int o = mt * 16 + pt;
        float sc = g4[o] * BN_INV;
        #pragma unroll
        for (int ks = 0; ks < 2; ++ks) {
            const float* src = W4 + o * 64 + ks * 32 + quad * 8;
            bf16x8 v;
            #pragma unroll
            for (int j = 0; j < 8; ++j) v[j] = (bf16_t)(src[j] * sc);
            A[mt][ks] = v;
        }
    }
    bf16x8 B0 = *(const bf16x8*)(mv  + T * 32 + quad * 8);  // channels 0..31 = maxv
    bf16x8 B1 = *(const bf16x8*)(fbf + T * 32 + quad * 8);  // channels 32..63 = f_self

    f32x4 acc[4] = {f32x4{0,0,0,0}, f32x4{0,0,0,0}, f32x4{0,0,0,0}, f32x4{0,0,0,0}};
    #pragma unroll
    for (int mt = 0; mt < 4; ++mt) {
        acc[mt] = MFMA16(A[mt][0], B0, acc[mt]);
        acc[mt] = MFMA16(A[mt][1], B1, acc[mt]);
    }
    #pragma unroll
    for (int mt = 0; mt < 4; ++mt)
        #pragma unroll
        for (int r = 0; r < 4; ++r) {
            int o = mt * 16 + quad * 4 + r;
            out[((size_t)b * 64 + o) * N + nn] = fmaxf(acc[mt][r] + b4[o], 0.f);
        }
}

// ---------------------------------------------------------------------------
extern "C" void kernel_launch(void* const* d_in, const int* in_sizes, int n_in,
                              void* d_out, int out_size, void* d_ws, size_t ws_size,
                              hipStream_t stream) {
    const float* feature = (const float*)d_in[0];
    const float* xyz     = (const float*)d_in[1];
    const int*   nidx    = (const int*)  d_in[2];
    const float* W1      = (const float*)d_in[3];
    const float* W2      = (const float*)d_in[4];
    const float* W3      = (const float*)d_in[5];
    const float* W4      = (const float*)d_in[6];
    const float* g1 = (const float*)d_in[7];
    const float* b1 = (const float*)d_in[8];
    const float* g2 = (const float*)d_in[9];
    const float* b2 = (const float*)d_in[10];
    const float* g3 = (const float*)d_in[11];
    const float* b3 = (const float*)d_in[12];
    const float* g4 = (const float*)d_in[13];
    const float* b4 = (const float*)d_in[14];
    float* out = (float*)d_out;

    const int B = 4;
    const int N = in_sizes[1] / (B * 3);
    const int total = B * N;

    bf16_t* fbf = (bf16_t*)d_ws;                 // [total][32] bf16 f table
    bf16_t* mvp = fbf + (size_t)total * 32;      // [total][32] bf16 maxv table

    const int nw16 = total / 16;                 // waves for k1/k3
    const int blk16 = (nw16 + 3) / 4;
    const int blk2 = (total + 4 * PPW - 1) / (4 * PPW);

    rfa_k1<<<blk16, 256, 0, stream>>>(feature, W2, g2, b2, fbf, N, nw16);
    rfa_k2<<<blk2, 256, 0, stream>>>(xyz, nidx, W1, g1, b1, W3, g3, b3,
                                     fbf, mvp, N, total);
    rfa_k3<<<blk16, 256, 0, stream>>>(mvp, fbf, W4, g4, b4, out, N, nw16);
}

// Round 3
// 193.518 us; speedup vs baseline: 2.6753x; 1.1591x over previous
//
#include <hip/hip_runtime.h>
#include <math.h>

typedef __bf16 bf16_t;
typedef bf16_t bf16x8 __attribute__((ext_vector_type(8)));
typedef bf16_t bf16x4 __attribute__((ext_vector_type(4)));
typedef float  f32x4  __attribute__((ext_vector_type(4)));

#define MFMA16(a, b, c) __builtin_amdgcn_mfma_f32_16x16x32_bf16(a, b, c, 0, 0, 0)

constexpr float BN_INV = 0.999995000037499687f;  // 1/sqrt(1+1e-5)
constexpr int G2 = 2;  // point-groups (of 16) per wave in k2

// ---------------------------------------------------------------------------
// K1: f = ReLU(BN(W2 @ feature)) -> bf16 table fbf[t][32]; also packs xyz into
// a float4 table so k2's random gathers are single 16B loads.
// One wave per 64 points (4 column tiles per A-frag load).
// ---------------------------------------------------------------------------
__global__ __launch_bounds__(256) void rfa_k1(
    const float* __restrict__ feature, const float* __restrict__ xyz,
    const float* __restrict__ W2,
    const float* __restrict__ g2, const float* __restrict__ b2,
    bf16_t* __restrict__ fbf, float4* __restrict__ xyz4,
    int N, int nwaves)
{
    int gtid = blockIdx.x * 256 + threadIdx.x;
    int w = gtid >> 6, lane = gtid & 63;
    if (w >= nwaves) return;
    int pt = lane & 15, quad = lane >> 4;
    int T0 = w * 64;
    int b  = T0 / N;
    int n0 = T0 - b * N;

    // xyz -> xyz4 (one point per lane)
    {
        size_t p = (size_t)T0 + lane;
        xyz4[p] = make_float4(xyz[p * 3], xyz[p * 3 + 1], xyz[p * 3 + 2], 0.f);
    }

    // A-frags: row h = mt*16 + (lane&15), k = ks*32 + quad*8 + j
    bf16x8 A[2][2];
    #pragma unroll
    for (int mt = 0; mt < 2; ++mt) {
        int h = mt * 16 + pt;
        float sc = g2[h] * BN_INV;
        #pragma unroll
        for (int ks = 0; ks < 2; ++ks) {
            const float* src = W2 + h * 64 + ks * 32 + quad * 8;
            bf16x8 v;
            #pragma unroll
            for (int j = 0; j < 8; ++j) v[j] = (bf16_t)(src[j] * sc);
            A[mt][ks] = v;
        }
    }
    float b2r[8];
    #pragma unroll
    for (int mt = 0; mt < 2; ++mt)
        #pragma unroll
        for (int r = 0; r < 4; ++r) b2r[mt * 4 + r] = b2[mt * 16 + quad * 4 + r];

    const float* fb = feature + (size_t)b * 64 * N;

    #pragma unroll
    for (int g = 0; g < 4; ++g) {
        int nn = n0 + g * 16 + pt;
        size_t T = (size_t)T0 + g * 16 + pt;
        bf16x8 Bf[2];
        #pragma unroll
        for (int ks = 0; ks < 2; ++ks) {
            bf16x8 v;
            #pragma unroll
            for (int j = 0; j < 8; ++j)
                v[j] = (bf16_t)fb[(size_t)(ks * 32 + quad * 8 + j) * N + nn];
            Bf[ks] = v;
        }
        f32x4 acc[2] = {f32x4{0,0,0,0}, f32x4{0,0,0,0}};
        #pragma unroll
        for (int mt = 0; mt < 2; ++mt) {
            acc[mt] = MFMA16(A[mt][0], Bf[0], acc[mt]);
            acc[mt] = MFMA16(A[mt][1], Bf[1], acc[mt]);
        }
        #pragma unroll
        for (int mt = 0; mt < 2; ++mt) {
            bf16x4 o;
            #pragma unroll
            for (int r = 0; r < 4; ++r)
                o[r] = (bf16_t)fmaxf(acc[mt][r] + b2r[mt * 4 + r], 0.f);
            *(bf16x4*)(fbf + T * 32 + mt * 16 + quad * 4) = o;
        }
    }
}

// ---------------------------------------------------------------------------
// K2 (fused with the final conv): 16 points in MFMA columns, loop over the 16
// neighbors. Per k: fx scalar (hoisted W1 algebra), fj 16B gather, 4 MFMA,
// 8-register max. Epilogue: bias+ReLU, LDS bounce (stride 18 = 2-way free),
// W4 MFMA from LDS-staged frags, coalesced fp32 stores.
// ---------------------------------------------------------------------------
__global__ __launch_bounds__(256) void rfa_k2(
    const float4* __restrict__ xyz4, const int* __restrict__ nidx,
    const float* __restrict__ W1, const float* __restrict__ g1, const float* __restrict__ b1,
    const float* __restrict__ W3, const float* __restrict__ g3, const float* __restrict__ b3,
    const float* __restrict__ W4, const float* __restrict__ g4, const float* __restrict__ b4,
    const bf16_t* __restrict__ fbf, float* __restrict__ out,
    int N, int ngroups)
{
    __shared__ __align__(16) bf16_t sW4[8 * 64 * 8];  // [(mt*2+ks)*64 + lane] -> bf16x8 frag
    __shared__ float sB[4][32 * 18];                   // per-wave bounce [ch][pt], stride 18

    int tid = threadIdx.x;
    // block-stage g4-folded W4 A-frags (frag f: o = (f>>1)*16 + n, k = (f&1)*32 + q*8 + j)
    for (int s = tid; s < 512; s += 256) {
        int f = s >> 6, l = s & 63;
        int mt = f >> 1, ks = f & 1, nn = l & 15, q = l >> 4;
        int o = mt * 16 + nn;
        float sc = g4[o] * BN_INV;
        const float* src = W4 + o * 64 + ks * 32 + q * 8;
        bf16x8 v;
        #pragma unroll
        for (int j = 0; j < 8; ++j) v[j] = (bf16_t)(src[j] * sc);
        *(bf16x8*)(sW4 + s * 8) = v;
    }
    __syncthreads();

    int lane = tid & 63, wv = tid >> 6;
    int n = lane & 15, quad = lane >> 4;

    // W3 A-frags (g3-folded), persistent
    bf16x8 A3[2][2];
    #pragma unroll
    for (int mt = 0; mt < 2; ++mt) {
        int h = mt * 16 + n;
        float sc = g3[h] * BN_INV;
        #pragma unroll
        for (int ks = 0; ks < 2; ++ks) {
            const float* src = W3 + h * 64 + ks * 32 + quad * 8;
            bf16x8 v;
            #pragma unroll
            for (int j = 0; j < 8; ++j) v[j] = (bf16_t)(src[j] * sc);
            A3[mt][ks] = v;
        }
    }
    // per-lane W1 algebra: channels c = quad*8 + j
    //   fx_c = ReLU( hoist_c + a_c*dist + V_c . nbr ),  hoist_c = b1 + U_c . self
    float a8[8], V0[8], V1[8], V2[8];
    #pragma unroll
    for (int j = 0; j < 8; ++j) {
        int c = quad * 8 + j;
        float s1 = g1[c] * BN_INV;
        const float* wp = W1 + c * 10;
        a8[j] = wp[0] * s1;
        V0[j] = (wp[7] - wp[1]) * s1;
        V1[j] = (wp[8] - wp[2]) * s1;
        V2[j] = (wp[9] - wp[3]) * s1;
    }
    float b3r[8];
    #pragma unroll
    for (int mt = 0; mt < 2; ++mt)
        #pragma unroll
        for (int r = 0; r < 4; ++r) b3r[mt * 4 + r] = b3[mt * 16 + quad * 4 + r];

    float* bounce = sB[wv];
    int wave_id = blockIdx.x * 4 + wv;

    for (int gi = 0; gi < G2; ++gi) {
        int grp = wave_id * G2 + gi;
        if (grp >= ngroups) break;               // wave-uniform
        int t0 = grp * 16;
        int b = t0 / N;
        int base = b * N;
        int nloc = t0 - base;

        float4 ps = xyz4[(size_t)t0 + n];        // self xyz (col point), 4-dup across quads
        float hoist[8];
        #pragma unroll
        for (int j = 0; j < 8; ++j) {
            int c = quad * 8 + j;
            float s1 = g1[c] * BN_INV;
            const float* wp = W1 + c * 10;
            hoist[j] = b1[c] + ((wp[1] + wp[4]) * ps.x + (wp[2] + wp[5]) * ps.y +
                                (wp[3] + wp[6]) * ps.z) * s1;
        }
        int4 myidx = *(const int4*)(nidx + (size_t)(t0 + n) * 16 + quad * 4);
        bf16x8 Bs = *(const bf16x8*)(fbf + (size_t)(t0 + n) * 32 + quad * 8);  // f_self frag

        f32x4 mx0 = {-3.0e38f, -3.0e38f, -3.0e38f, -3.0e38f};
        f32x4 mx1 = {-3.0e38f, -3.0e38f, -3.0e38f, -3.0e38f};

        #pragma unroll
        for (int k = 0; k < 16; ++k) {
            const int comp = k & 3;
            int src = (comp == 0) ? myidx.x : (comp == 1) ? myidx.y
                     : (comp == 2) ? myidx.z : myidx.w;
            // broadcast idx[n][k] to all quads of column n
            int j = __builtin_amdgcn_ds_bpermute(n * 4 + (k >> 2) * 64, src);

            float4 pn = xyz4[(size_t)base + j];
            float rx = ps.x - pn.x, ry = ps.y - pn.y, rz = ps.z - pn.z;
            float dist = sqrtf(rx * rx + ry * ry + rz * rz);

            bf16x8 Bx;
            #pragma unroll
            for (int c = 0; c < 8; ++c) {
                float v = hoist[c] + a8[c] * dist;
                v = fmaf(V0[c], pn.x, v);
                v = fmaf(V1[c], pn.y, v);
                v = fmaf(V2[c], pn.z, v);
                Bx[c] = (bf16_t)fmaxf(v, 0.f);
            }
            bf16x8 Bj = *(const bf16x8*)(fbf + (size_t)(base + j) * 32 + quad * 8);

            f32x4 ac0 = {0,0,0,0}, ac1 = {0,0,0,0};
            ac0 = MFMA16(A3[0][0], Bj, ac0);
            ac0 = MFMA16(A3[0][1], Bx, ac0);
            ac1 = MFMA16(A3[1][0], Bj, ac1);
            ac1 = MFMA16(A3[1][1], Bx, ac1);
            #pragma unroll
            for (int r = 0; r < 4; ++r) {
                mx0[r] = fmaxf(mx0[r], ac0[r]);
                mx1[r] = fmaxf(mx1[r], ac1[r]);
            }
        }

        // epilogue: bias+ReLU on max, bounce to channel-major, W4 MFMA, store
        #pragma unroll
        for (int r = 0; r < 4; ++r) {
            bounce[(quad * 4 + r) * 18 + n]      = fmaxf(mx0[r] + b3r[r], 0.f);
            bounce[(16 + quad * 4 + r) * 18 + n] = fmaxf(mx1[r] + b3r[4 + r], 0.f);
        }
        asm volatile("s_waitcnt lgkmcnt(0)" ::: "memory");
        bf16x8 Bm;
        #pragma unroll
        for (int jj = 0; jj < 8; ++jj)
            Bm[jj] = (bf16_t)bounce[(quad * 8 + jj) * 18 + n];

        #pragma unroll
        for (int mt = 0; mt < 4; ++mt) {
            bf16x8 A40 = *(const bf16x8*)(sW4 + ((size_t)(mt * 2 + 0) * 64 + lane) * 8);
            bf16x8 A41 = *(const bf16x8*)(sW4 + ((size_t)(mt * 2 + 1) * 64 + lane) * 8);
            f32x4 acc = {0,0,0,0};
            acc = MFMA16(A40, Bm, acc);
            acc = MFMA16(A41, Bs, acc);
            #pragma unroll
            for (int r = 0; r < 4; ++r) {
                int o = mt * 16 + quad * 4 + r;
                out[((size_t)b * 64 + o) * N + nloc + n] = fmaxf(acc[r] + b4[o], 0.f);
            }
        }
        asm volatile("s_waitcnt lgkmcnt(0)" ::: "memory");  // drain before next group's bounce
    }
}

// ---------------------------------------------------------------------------
extern "C" void kernel_launch(void* const* d_in, const int* in_sizes, int n_in,
                              void* d_out, int out_size, void* d_ws, size_t ws_size,
                              hipStream_t stream) {
    const float* feature = (const float*)d_in[0];
    const float* xyz     = (const float*)d_in[1];
    const int*   nidx    = (const int*)  d_in[2];
    const float* W1      = (const float*)d_in[3];
    const float* W2      = (const float*)d_in[4];
    const float* W3      = (const float*)d_in[5];
    const float* W4      = (const float*)d_in[6];
    const float* g1 = (const float*)d_in[7];
    const float* b1 = (const float*)d_in[8];
    const float* g2 = (const float*)d_in[9];
    const float* b2 = (const float*)d_in[10];
    const float* g3 = (const float*)d_in[11];
    const float* b3 = (const float*)d_in[12];
    const float* g4 = (const float*)d_in[13];
    const float* b4 = (const float*)d_in[14];
    float* out = (float*)d_out;

    const int B = 4;
    const int N = in_sizes[1] / (B * 3);
    const int total = B * N;                      // 163840

    bf16_t* fbf  = (bf16_t*)d_ws;                 // [total][32] bf16   (10.5 MB)
    float4* xyz4 = (float4*)((char*)d_ws + (size_t)total * 32 * sizeof(bf16_t));

    const int nw1 = total / 64;                   // 2560 waves
    const int blk1 = (nw1 + 3) / 4;
    const int ngroups = total / 16;               // 10240
    const int nw2 = (ngroups + G2 - 1) / G2;      // 5120 waves
    const int blk2 = (nw2 + 3) / 4;

    rfa_k1<<<blk1, 256, 0, stream>>>(feature, xyz, W2, g2, b2, fbf, xyz4, N, nw1);
    rfa_k2<<<blk2, 256, 0, stream>>>(xyz4, nidx, W1, g1, b1, W3, g3, b3, W4, g4, b4,
                                     fbf, out, N, ngroups);
}